// Round 7
// baseline (868.441 us; speedup 1.0000x reference)
//
#include <hip/hip_runtime.h>

// Talking-heads attention, fully fused two-phase flash-style implementation.
// b=16, n=1024, dim=768, h=12, d=64.  All staged tensors fp16, MFMA 16x16x32 f16.
//
// Pipeline:
//  1. k_cast_x     : x (f32) -> xb (f16)
//  2. k_prep_w     : Wt = [Wq*SCALE | Wkv]^T (f16, N-major), WoT = Wo^T (f16)
//  3. k_gemm_qkv   : [q|k|v] = xb @ Wt, scattered to per-head [b][h][n][64] f16
//  4. k_transpose_v: vt[b][h][d][n] (so PV B-fragments are contiguous)
//  5. k_attn       : per (b, 16-row i-tile), see header comment at the kernel
//  6. k_gemm_out   : out = obuf @ WoT + bo (f32)
//
// Workspace layout (bytes), total 105,381,888:
//   xb   @ 0          (25,165,824)   -- reused as vt after gemm_qkv
//   Wt   @ 25165824   ( 3,538,944)
//   WoT  @ 28704768   ( 1,179,648)
//   qb   @ 29884416   (25,165,824)
//   kb   @ 55050240   (25,165,824)
//   vb   @ 80216064   (25,165,824)   -- reused as obuf after transpose

typedef _Float16 f16;
typedef _Float16 f16x8 __attribute__((ext_vector_type(8)));
typedef _Float16 f16x4 __attribute__((ext_vector_type(4)));
typedef float f32x4 __attribute__((ext_vector_type(4)));
typedef float fv4 __attribute__((ext_vector_type(4)));

#define MFMA(a, b, c) __builtin_amdgcn_mfma_f32_16x16x32_f16(a, b, c, 0, 0, 0)
#define MFMA16(a, b, c) __builtin_amdgcn_mfma_f32_16x16x16f16(a, b, c, 0, 0, 0)

// ---------------------------------------------------------------- cast x -> f16
__global__ __launch_bounds__(256) void k_cast_x(const float* __restrict__ x,
                                                f16* __restrict__ xb) {
  int idx = (blockIdx.x * 256 + threadIdx.x) * 8;
  fv4 a = *(const fv4*)(x + idx);
  fv4 b = *(const fv4*)(x + idx + 4);
  f16x8 o;
  o[0] = (f16)a[0]; o[1] = (f16)a[1]; o[2] = (f16)a[2]; o[3] = (f16)a[3];
  o[4] = (f16)b[0]; o[5] = (f16)b[1]; o[6] = (f16)b[2]; o[7] = (f16)b[3];
  *(f16x8*)(xb + idx) = o;
}

// ------------------------------------------- weights: transpose + cast (+scale q)
__global__ __launch_bounds__(256) void k_prep_w(const float* __restrict__ Wq,
                                                const float* __restrict__ Wkv,
                                                const float* __restrict__ Wo,
                                                f16* __restrict__ Wt,
                                                f16* __restrict__ WoT) {
  int idx = blockIdx.x * 256 + threadIdx.x;
  if (idx < 2304 * 768) {
    int n = idx / 768, k = idx % 768;
    float v = (n < 768) ? Wq[k * 768 + n] * 0.125f   // SCALE = 64^-0.5 folded here
                        : Wkv[k * 1536 + (n - 768)];
    Wt[idx] = (f16)v;
  } else {
    int id2 = idx - 2304 * 768;
    int n = id2 / 768, k = id2 % 768;
    WoT[id2] = (f16)Wo[k * 768 + n];
  }
}

// ---------------------------------------------------------------- QKV projection
__global__ __launch_bounds__(256) void k_gemm_qkv(const f16* __restrict__ A,
                                                  const f16* __restrict__ Bt,
                                                  f16* __restrict__ qb,
                                                  f16* __restrict__ kb,
                                                  f16* __restrict__ vb) {
  __shared__ f16 As[128 * 72];  // +8 pad: conflict-free b128 frag reads
  __shared__ f16 Bs[128 * 72];
  const int tid = threadIdx.x;
  const int m0 = blockIdx.y << 7;
  const int n0 = blockIdx.x << 7;
  const int lane = tid & 63, w = tid >> 6;
  const int quad = lane >> 4, col = lane & 15;
  const int wm = (w >> 1) << 6, wn = (w & 1) << 6;
  const f32x4 z4 = {0.f, 0.f, 0.f, 0.f};
  f32x4 acc[4][4];
#pragma unroll
  for (int i = 0; i < 4; ++i)
#pragma unroll
    for (int j = 0; j < 4; ++j) acc[i][j] = z4;

  for (int k0 = 0; k0 < 768; k0 += 64) {
#pragma unroll
    for (int s = 0; s < 4; ++s) {
      int u = s * 256 + tid;
      int row = u >> 3, seg = (u & 7) << 3;
      *(f16x8*)&As[row * 72 + seg] = *(const f16x8*)(A + (m0 + row) * 768 + k0 + seg);
      *(f16x8*)&Bs[row * 72 + seg] = *(const f16x8*)(Bt + (n0 + row) * 768 + k0 + seg);
    }
    __syncthreads();
#pragma unroll
    for (int kk = 0; kk < 64; kk += 32) {
      f16x8 af[4], bf[4];
#pragma unroll
      for (int ic = 0; ic < 4; ++ic)
        af[ic] = *(f16x8*)&As[(wm + ic * 16 + col) * 72 + kk + quad * 8];
#pragma unroll
      for (int jc = 0; jc < 4; ++jc)
        bf[jc] = *(f16x8*)&Bs[(wn + jc * 16 + col) * 72 + kk + quad * 8];
#pragma unroll
      for (int ic = 0; ic < 4; ++ic)
#pragma unroll
        for (int jc = 0; jc < 4; ++jc) acc[ic][jc] = MFMA(af[ic], bf[jc], acc[ic][jc]);
    }
    __syncthreads();
  }
  // epilogue: scatter to per-head q/k/v layouts
#pragma unroll
  for (int jc = 0; jc < 4; ++jc) {
    int gn = n0 + wn + jc * 16 + col;
#pragma unroll
    for (int ic = 0; ic < 4; ++ic)
#pragma unroll
      for (int r = 0; r < 4; ++r) {
        int gm = m0 + wm + ic * 16 + (quad << 2) + r;
        int b = gm >> 10, i = gm & 1023;
        f16 v = (f16)acc[ic][jc][r];
        if (gn < 768) {
          int h = gn >> 6, dd = gn & 63;
          qb[(((b * 12 + h) << 10) + i) * 64 + dd] = v;
        } else if (gn < 1536) {
          int t = gn - 768; int h = t >> 6, dd = t & 63;
          kb[(((b * 12 + h) << 10) + i) * 64 + dd] = v;
        } else {
          int t = gn - 1536; int h = t >> 6, dd = t & 63;
          vb[(((b * 12 + h) << 10) + i) * 64 + dd] = v;
        }
      }
  }
}

// ---------------------------------------------------------------- V transpose
__global__ __launch_bounds__(256) void k_transpose_v(const f16* __restrict__ vb,
                                                     f16* __restrict__ vt) {
  __shared__ f16 t[64 * 72];
  const int bh = blockIdx.x;        // 0..191
  const int n0 = blockIdx.y << 6;   // 16 tiles of 64
  const int tid = threadIdx.x;
#pragma unroll
  for (int s = 0; s < 2; ++s) {
    int u = s * 256 + tid;
    int r = u >> 3, c = (u & 7) << 3;
    *(f16x8*)&t[r * 72 + c] = *(const f16x8*)(vb + (bh * 1024 + n0 + r) * 64 + c);
  }
  __syncthreads();
#pragma unroll
  for (int s = 0; s < 2; ++s) {
    int u = s * 256 + tid;
    int d = u >> 3, c = (u & 7) << 3;
    f16x8 o;
#pragma unroll
    for (int e = 0; e < 8; ++e) o[e] = t[(c + e) * 72 + d];
    *(f16x8*)(vt + (bh * 64 + d) * 1024 + n0 + c) = o;
  }
}

// ---------------------------------------------------------------- fused attention v6
// block = 256 thr (4 waves) handles (b, 16 query rows).  Wave w owns j-quarter
// jw=w*16 of each 64-j tile for ALL 12 heads.
// KEY CHANGE vs v5 (which stalled ~20k of 21k cycles per iteration; all pipes
// <18%): CROSS-ITERATION SOFTWARE PIPELINE.  Occupancy is LDS-limited (73KB ->
// 2 blocks/CU), so VGPRs are free up to 256/wave.  We spend 96 of them on a
// full K-tile register buffer kr[12][2]:
//   computeS(kr_j0)  ->  issue loads kr <- K(j0+64)  ->  t-loop + PV compute
// so the next tile's 24 K loads are in flight UNDER the ~1-2k cycles of mix/
// softmax/PV work, instead of draining serially at the top of each iteration.
// Also: t-loop ds_reads fully batched (sB[16], one lgkm drain), PV vt loads
// 2-deep rotated across heads, setprio dropped (lock-step waves).
// Everything else identical to v5: Q in LDS (24KB XOR-swizzled), S staged in
// wave-local LDS b64 units (conflict-free), maxless softmax, post-mix
// in-register via MFMA16, Pm exchange XOR-swizzled, 2 barriers per iteration.
__global__ __launch_bounds__(256, 2) void k_attn(
    const f16* __restrict__ qb, const f16* __restrict__ kb, const f16* __restrict__ vt,
    const float* __restrict__ mixp, const float* __restrict__ mixq,
    f16* __restrict__ ob) {
  extern __shared__ f16 smem[];
  f16* Qs   = smem;            // [12][16][64] f16, 16B-unit XOR swizzle (24KB)
  f16* Slds = smem + 12288;    // 4 waves x 3200 f16: [16 j][3 hgrp][16 u][4] + zeros
  f16* Pmb  = smem + 25088;    // [g'][i][16 units][4] f16 (24KB)

  const int tid = threadIdx.x;
  const int bid0 = blockIdx.x;
  const int xcd = bid0 & 7, idx = bid0 >> 3;
  const int b = ((idx >> 6) << 3) | xcd;   // one b per XCD at a time (L2-resident)
  const int i0 = (idx & 63) << 4;
  const int lane = tid & 63;
  const int w = tid >> 6;
  const int quad = lane >> 4, col = lane & 15;
  const int q4 = quad << 2;
  const int w3 = w * 3;
  const int jw = w << 4;  // wave's j offset within a 64-j iteration
  const f32x4 z4 = {0.f, 0.f, 0.f, 0.f};

  // mix fragments for 16x16x16: lane holds k-slots h = quad*4+e.
  // b_pre : A[m=g=col][k=h]   = mixp[h][g]   (mixp^T)
  // b_post: B[k=g][n=g'=col]  = mixq[g][g']
  f16x4 b_pre, b_post;
#pragma unroll
  for (int e = 0; e < 4; ++e) {
    int hk = q4 + e;
    bool ok = (hk < 12) && (col < 12);
    b_pre[e]  = ok ? (f16)mixp[hk * 12 + col] : (f16)0.f;
    b_post[e] = ok ? (f16)mixq[hk * 12 + col] : (f16)0.f;
  }

  f16* Sw = &Slds[w * 3200];
  // zero block at Sw[3072..3135]: pre-mix k-slots 12..15 (quad==3) read here
  if (lane < 16) {
    f16x4 z; z[0] = (f16)0.f; z[1] = (f16)0.f; z[2] = (f16)0.f; z[3] = (f16)0.f;
    *(f16x4*)&Sw[3072 + lane * 4] = z;
  }

  // stage Q tile -> Qs: Q[h][i][d], d in 8 units of 8 f16, unit stored at u^(i&7)
#pragma unroll
  for (int s = 0; s < 6; ++s) {
    int u = s * 256 + tid;                       // 0..1535
    int h = u >> 7, i = (u >> 3) & 15, uu = u & 7;
    f16x8 q = *(const f16x8*)(qb + ((((b * 12 + h) << 10) + i0 + i) << 6) + uu * 8);
    *(f16x8*)&Qs[(((h << 4) + i) << 6) + ((uu ^ (i & 7)) << 3)] = q;
  }
  __syncthreads();

  // K-tile register buffer (96 VGPR) + loaders / consumers
  f16x8 kr[12][2];
  auto loadK = [&](int j0) {
#pragma unroll
    for (int h = 0; h < 12; ++h) {
      const f16* kbase = kb + ((((b * 12 + h) << 10) + j0 + jw + col) << 6);
      kr[h][0] = *(const f16x8*)(kbase + quad * 8);
      kr[h][1] = *(const f16x8*)(kbase + 32 + quad * 8);
    }
  };
  // QK^T for all 12 heads on this wave's 16 j's from kr; S -> wave-local LDS.
  // unit (j=col, i=q4+r, hgrp) at Sw[j*192 + hg*64 + ((i+j)&15)*4], content h asc.
  auto computeS = [&]() {
#pragma unroll
    for (int hg = 0; hg < 3; ++hg) {
      f32x4 s4[4];
#pragma unroll
      for (int e = 0; e < 4; ++e) {
        int h = hg * 4 + e;
        f16x8 q0 = *(const f16x8*)&Qs[(((h << 4) + col) << 6) +
                                      ((quad ^ (col & 7)) << 3)];
        f16x8 q1 = *(const f16x8*)&Qs[(((h << 4) + col) << 6) +
                                      (((4 + quad) ^ (col & 7)) << 3)];
        f32x4 a = MFMA(q0, kr[h][0], z4);
        s4[e] = MFMA(q1, kr[h][1], a);
      }
#pragma unroll
      for (int r = 0; r < 4; ++r) {
        f16x4 p;
        p[0] = (f16)s4[0][r]; p[1] = (f16)s4[1][r];
        p[2] = (f16)s4[2][r]; p[3] = (f16)s4[3][r];
        *(f16x4*)&Sw[col * 192 + hg * 64 + ((q4 + r + col) & 15) * 4] = p;
      }
    }
  };
  // pre-mix B-frag read address: k-slot group = quad (hgrp), or zero block
  auto sread = [&](int t) -> f16x4 {
    int zi = (quad < 3) ? (t * 192 + quad * 64 + ((col + t) & 15) * 4)
                        : (3072 + ((col + t) & 15) * 4);
    return *(const f16x4*)&Sw[zi];
  };

  // ---------------- phase 1: denominators l per (g,i), fully per-lane, 0 barriers
  float l_run[4] = {0.f, 0.f, 0.f, 0.f};
  loadK(0);
  for (int j0 = 0; j0 < 1024; j0 += 64) {
    computeS();
    if (j0 + 64 < 1024) loadK(j0 + 64);   // next K tile flies under the t-loop
    f16x4 sB[16];
#pragma unroll
    for (int t = 0; t < 16; ++t) sB[t] = sread(t);
#pragma unroll
    for (int t = 0; t < 16; ++t) {
      f32x4 d1 = MFMA16(b_pre, sB[t], z4);
#pragma unroll
      for (int r = 0; r < 4; ++r) l_run[r] += __expf(d1[r]);
    }
  }
  // merge partial l across the 4 waves (disjoint j quarters)
  float* Lb = (float*)Pmb;  // [w][g(16)][i(16)] overlay, phase-boundary only
#pragma unroll
  for (int r = 0; r < 4; ++r) Lb[(w * 16 + q4 + r) * 16 + col] = l_run[r];
  __syncthreads();
  float il[4];
#pragma unroll
  for (int r = 0; r < 4; ++r) {
    float s = 0.f;
#pragma unroll
    for (int ww = 0; ww < 4; ++ww) s += Lb[(ww * 16 + q4 + r) * 16 + col];
    il[r] = 1.f / s;
  }
  __syncthreads();  // Lb region handed back to Pm

  // ---------------- phase 2: recompute d1, P, post-mix, PV
  f32x4 oa[3][4];
#pragma unroll
  for (int g = 0; g < 3; ++g)
#pragma unroll
    for (int dc = 0; dc < 4; ++dc) oa[g][dc] = z4;

  f16x8 vrA[2][4], vrB[2][4];
  auto loadV = [&](f16x8 (&vr)[2][4], int gp, int j0) {
#pragma unroll
    for (int jh = 0; jh < 2; ++jh)
#pragma unroll
      for (int dc = 0; dc < 4; ++dc)
        vr[jh][dc] = *(const f16x8*)(vt + ((((b * 12 + gp) << 6) + dc * 16 + col) << 10) +
                                     j0 + jh * 32 + quad * 8);
  };
  auto pvHead = [&](f16x8 (&vr)[2][4], int gg) {
    int gp = w3 + gg;
    int k4r = (gp + col) & 15;
#pragma unroll
    for (int jh = 0; jh < 2; ++jh) {
      int ub = (jh * 4 + quad) * 2;
      f16x4 lo = *(const f16x4*)&Pmb[(((gp << 4) + col) * 16 + (ub ^ k4r)) * 4];
      f16x4 hi = *(const f16x4*)&Pmb[(((gp << 4) + col) * 16 + ((ub + 1) ^ k4r)) * 4];
      f16x8 aP = __builtin_shufflevector(lo, hi, 0, 1, 2, 3, 4, 5, 6, 7);
#pragma unroll
      for (int dc = 0; dc < 4; ++dc)
        oa[gg][dc] = MFMA(aP, vr[jh][dc], oa[gg][dc]);
    }
  };

  loadK(0);
  for (int j0 = 0; j0 < 1024; j0 += 64) {
    computeS();
    if (j0 + 64 < 1024) loadK(j0 + 64);   // next K tile flies under t-loop + PV
    f16x4 sB[16];
#pragma unroll
    for (int t = 0; t < 16; ++t) sB[t] = sread(t);
#pragma unroll
    for (int tt = 0; tt < 4; ++tt) {  // 4 tiles per Pm flush
      f16x4 pk[4];
#pragma unroll
      for (int t4 = 0; t4 < 4; ++t4) {
        int t = tt * 4 + t4;
        f32x4 d1 = MFMA16(b_pre, sB[t], z4);
        f16x4 pA;
#pragma unroll
        for (int r = 0; r < 4; ++r) pA[r] = (f16)(__expf(d1[r]) * il[r]);
        f32x4 d2 = MFMA16(pA, b_post, z4);  // lane: (i=q4+r, g'=col, j=t)
#pragma unroll
        for (int r = 0; r < 4; ++r) pk[r][t4] = (f16)d2[r];
      }
      // flush unit (w*4+tt) of row (g'=col, i=q4+r), XOR-swizzled
      if (col < 12) {
#pragma unroll
        for (int r = 0; r < 4; ++r) {
          int k4 = (col + q4 + r) & 15;
          *(f16x4*)&Pmb[(((col << 4) + q4 + r) * 16 + ((w * 4 + tt) ^ k4)) * 4] = pk[r];
        }
      }
    }
    __syncthreads();  // Pm complete (all 64 j from all waves)
    // PV: wave w owns heads 3w..3w+2; vt loads 2-deep rotated across heads
    loadV(vrA, w3 + 0, j0);
    loadV(vrB, w3 + 1, j0);
    pvHead(vrA, 0);
    loadV(vrA, w3 + 2, j0);
    pvHead(vrB, 1);
    pvHead(vrA, 2);
    __syncthreads();  // Pm consumed before next iteration overwrites
  }

  // epilogue: O (C-layout: row=q4+r = i, col = d) -> obuf [b][n][768]
#pragma unroll
  for (int gg = 0; gg < 3; ++gg) {
    int gp = w3 + gg;
#pragma unroll
    for (int dc = 0; dc < 4; ++dc)
#pragma unroll
      for (int r = 0; r < 4; ++r)
        ob[((b << 10) + i0 + q4 + r) * 768 + gp * 64 + dc * 16 + col] =
            (f16)oa[gg][dc][r];
  }
}

// ---------------------------------------------------------------- output GEMM
__global__ __launch_bounds__(256) void k_gemm_out(const f16* __restrict__ A,
                                                  const f16* __restrict__ Bt,
                                                  const float* __restrict__ bias,
                                                  float* __restrict__ out) {
  __shared__ f16 As[128 * 72];
  __shared__ f16 Bs[128 * 72];
  const int tid = threadIdx.x;
  const int m0 = blockIdx.y << 7;
  const int n0 = blockIdx.x << 7;
  const int lane = tid & 63, w = tid >> 6;
  const int quad = lane >> 4, col = lane & 15;
  const int wm = (w >> 1) << 6, wn = (w & 1) << 6;
  const f32x4 z4 = {0.f, 0.f, 0.f, 0.f};
  f32x4 acc[4][4];
#pragma unroll
  for (int i = 0; i < 4; ++i)
#pragma unroll
    for (int j = 0; j < 4; ++j) acc[i][j] = z4;

  for (int k0 = 0; k0 < 768; k0 += 64) {
#pragma unroll
    for (int s = 0; s < 4; ++s) {
      int u = s * 256 + tid;
      int row = u >> 3, seg = (u & 7) << 3;
      *(f16x8*)&As[row * 72 + seg] = *(const f16x8*)(A + (m0 + row) * 768 + k0 + seg);
      *(f16x8*)&Bs[row * 72 + seg] = *(const f16x8*)(Bt + (n0 + row) * 768 + k0 + seg);
    }
    __syncthreads();
#pragma unroll
    for (int kk = 0; kk < 64; kk += 32) {
      f16x8 af[4], bf[4];
#pragma unroll
      for (int ic = 0; ic < 4; ++ic)
        af[ic] = *(f16x8*)&As[(wm + ic * 16 + col) * 72 + kk + quad * 8];
#pragma unroll
      for (int jc = 0; jc < 4; ++jc)
        bf[jc] = *(f16x8*)&Bs[(wn + jc * 16 + col) * 72 + kk + quad * 8];
#pragma unroll
      for (int ic = 0; ic < 4; ++ic)
#pragma unroll
        for (int jc = 0; jc < 4; ++jc) acc[ic][jc] = MFMA(af[ic], bf[jc], acc[ic][jc]);
    }
    __syncthreads();
  }
#pragma unroll
  for (int jc = 0; jc < 4; ++jc) {
    int gn = n0 + wn + jc * 16 + col;
    float bv = bias[gn];
#pragma unroll
    for (int ic = 0; ic < 4; ++ic)
#pragma unroll
      for (int r = 0; r < 4; ++r) {
        int gm = m0 + wm + ic * 16 + (quad << 2) + r;
        out[gm * 768 + gn] = acc[ic][jc][r] + bv;
      }
  }
}

// ---------------------------------------------------------------- launcher
extern "C" void kernel_launch(void* const* d_in, const int* in_sizes, int n_in,
                              void* d_out, int out_size, void* d_ws, size_t ws_size,
                              hipStream_t stream) {
  const float* x    = (const float*)d_in[0];
  const float* Wq   = (const float*)d_in[1];
  const float* Wkv  = (const float*)d_in[2];
  const float* mixp = (const float*)d_in[3];
  const float* mixq = (const float*)d_in[4];
  const float* Wo   = (const float*)d_in[5];
  const float* bo   = (const float*)d_in[6];
  float* out = (float*)d_out;

  char* ws = (char*)d_ws;
  f16* xb  = (f16*)(ws);
  f16* Wt  = (f16*)(ws + 25165824);
  f16* WoT = (f16*)(ws + 28704768);
  f16* qb  = (f16*)(ws + 29884416);
  f16* kb  = (f16*)(ws + 55050240);
  f16* vb  = (f16*)(ws + 80216064);
  f16* vt  = xb;   // xb dead after k_gemm_qkv
  f16* obuf = vb;  // vb dead after k_transpose_v

  k_cast_x<<<dim3(6144), dim3(256), 0, stream>>>(x, xb);
  k_prep_w<<<dim3(9216), dim3(256), 0, stream>>>(Wq, Wkv, Wo, Wt, WoT);
  k_gemm_qkv<<<dim3(18, 128), dim3(256), 0, stream>>>(xb, Wt, qb, kb, vb);
  k_transpose_v<<<dim3(192, 16), dim3(256), 0, stream>>>(vb, vt);
  k_attn<<<dim3(1024), dim3(256), 74752, stream>>>(qb, kb, vt, mixp, mixq, obuf);
  k_gemm_out<<<dim3(6, 128), dim3(256), 0, stream>>>(obuf, WoT, bo, out);
}

// Round 8
// 859.575 us; speedup vs baseline: 1.0103x; 1.0103x over previous
//
#include <hip/hip_runtime.h>

// Talking-heads attention, fully fused two-phase flash-style implementation.
// b=16, n=1024, dim=768, h=12, d=64.  All staged tensors fp16, MFMA 16x16x32 f16.
//
// Pipeline:
//  1. k_cast_x     : x (f32) -> xb (f16)
//  2. k_prep_w     : Wt = [Wq*SCALE | Wkv]^T (f16, N-major), WoT = Wo^T (f16)
//  3. k_gemm_qkv   : [q|k|v] = xb @ Wt, scattered to per-head [b][h][n][64] f16
//  4. k_transpose_v: vt[b][h][d][n] (so PV B-fragments are contiguous)
//  5. k_attn       : per (b, 16-row i-tile), see header comment at the kernel
//  6. k_gemm_out   : out = obuf @ WoT + bo (f32)
//
// Workspace layout (bytes), total 105,381,888:
//   xb   @ 0          (25,165,824)   -- reused as vt after gemm_qkv
//   Wt   @ 25165824   ( 3,538,944)
//   WoT  @ 28704768   ( 1,179,648)
//   qb   @ 29884416   (25,165,824)
//   kb   @ 55050240   (25,165,824)
//   vb   @ 80216064   (25,165,824)   -- reused as obuf after transpose

typedef _Float16 f16;
typedef _Float16 f16x8 __attribute__((ext_vector_type(8)));
typedef _Float16 f16x4 __attribute__((ext_vector_type(4)));
typedef float f32x4 __attribute__((ext_vector_type(4)));
typedef float fv4 __attribute__((ext_vector_type(4)));

#define MFMA(a, b, c) __builtin_amdgcn_mfma_f32_16x16x32_f16(a, b, c, 0, 0, 0)
#define MFMA16(a, b, c) __builtin_amdgcn_mfma_f32_16x16x16f16(a, b, c, 0, 0, 0)

// ---------------------------------------------------------------- cast x -> f16
__global__ __launch_bounds__(256) void k_cast_x(const float* __restrict__ x,
                                                f16* __restrict__ xb) {
  int idx = (blockIdx.x * 256 + threadIdx.x) * 8;
  fv4 a = *(const fv4*)(x + idx);
  fv4 b = *(const fv4*)(x + idx + 4);
  f16x8 o;
  o[0] = (f16)a[0]; o[1] = (f16)a[1]; o[2] = (f16)a[2]; o[3] = (f16)a[3];
  o[4] = (f16)b[0]; o[5] = (f16)b[1]; o[6] = (f16)b[2]; o[7] = (f16)b[3];
  *(f16x8*)(xb + idx) = o;
}

// ------------------------------------------- weights: transpose + cast (+scale q)
__global__ __launch_bounds__(256) void k_prep_w(const float* __restrict__ Wq,
                                                const float* __restrict__ Wkv,
                                                const float* __restrict__ Wo,
                                                f16* __restrict__ Wt,
                                                f16* __restrict__ WoT) {
  int idx = blockIdx.x * 256 + threadIdx.x;
  if (idx < 2304 * 768) {
    int n = idx / 768, k = idx % 768;
    float v = (n < 768) ? Wq[k * 768 + n] * 0.125f   // SCALE = 64^-0.5 folded here
                        : Wkv[k * 1536 + (n - 768)];
    Wt[idx] = (f16)v;
  } else {
    int id2 = idx - 2304 * 768;
    int n = id2 / 768, k = id2 % 768;
    WoT[id2] = (f16)Wo[k * 768 + n];
  }
}

// ---------------------------------------------------------------- QKV projection
__global__ __launch_bounds__(256) void k_gemm_qkv(const f16* __restrict__ A,
                                                  const f16* __restrict__ Bt,
                                                  f16* __restrict__ qb,
                                                  f16* __restrict__ kb,
                                                  f16* __restrict__ vb) {
  __shared__ f16 As[128 * 72];  // +8 pad: conflict-free b128 frag reads
  __shared__ f16 Bs[128 * 72];
  const int tid = threadIdx.x;
  const int m0 = blockIdx.y << 7;
  const int n0 = blockIdx.x << 7;
  const int lane = tid & 63, w = tid >> 6;
  const int quad = lane >> 4, col = lane & 15;
  const int wm = (w >> 1) << 6, wn = (w & 1) << 6;
  const f32x4 z4 = {0.f, 0.f, 0.f, 0.f};
  f32x4 acc[4][4];
#pragma unroll
  for (int i = 0; i < 4; ++i)
#pragma unroll
    for (int j = 0; j < 4; ++j) acc[i][j] = z4;

  for (int k0 = 0; k0 < 768; k0 += 64) {
#pragma unroll
    for (int s = 0; s < 4; ++s) {
      int u = s * 256 + tid;
      int row = u >> 3, seg = (u & 7) << 3;
      *(f16x8*)&As[row * 72 + seg] = *(const f16x8*)(A + (m0 + row) * 768 + k0 + seg);
      *(f16x8*)&Bs[row * 72 + seg] = *(const f16x8*)(Bt + (n0 + row) * 768 + k0 + seg);
    }
    __syncthreads();
#pragma unroll
    for (int kk = 0; kk < 64; kk += 32) {
      f16x8 af[4], bf[4];
#pragma unroll
      for (int ic = 0; ic < 4; ++ic)
        af[ic] = *(f16x8*)&As[(wm + ic * 16 + col) * 72 + kk + quad * 8];
#pragma unroll
      for (int jc = 0; jc < 4; ++jc)
        bf[jc] = *(f16x8*)&Bs[(wn + jc * 16 + col) * 72 + kk + quad * 8];
#pragma unroll
      for (int ic = 0; ic < 4; ++ic)
#pragma unroll
        for (int jc = 0; jc < 4; ++jc) acc[ic][jc] = MFMA(af[ic], bf[jc], acc[ic][jc]);
    }
    __syncthreads();
  }
  // epilogue: scatter to per-head q/k/v layouts
#pragma unroll
  for (int jc = 0; jc < 4; ++jc) {
    int gn = n0 + wn + jc * 16 + col;
#pragma unroll
    for (int ic = 0; ic < 4; ++ic)
#pragma unroll
      for (int r = 0; r < 4; ++r) {
        int gm = m0 + wm + ic * 16 + (quad << 2) + r;
        int b = gm >> 10, i = gm & 1023;
        f16 v = (f16)acc[ic][jc][r];
        if (gn < 768) {
          int h = gn >> 6, dd = gn & 63;
          qb[(((b * 12 + h) << 10) + i) * 64 + dd] = v;
        } else if (gn < 1536) {
          int t = gn - 768; int h = t >> 6, dd = t & 63;
          kb[(((b * 12 + h) << 10) + i) * 64 + dd] = v;
        } else {
          int t = gn - 1536; int h = t >> 6, dd = t & 63;
          vb[(((b * 12 + h) << 10) + i) * 64 + dd] = v;
        }
      }
  }
}

// ---------------------------------------------------------------- V transpose
__global__ __launch_bounds__(256) void k_transpose_v(const f16* __restrict__ vb,
                                                     f16* __restrict__ vt) {
  __shared__ f16 t[64 * 72];
  const int bh = blockIdx.x;        // 0..191
  const int n0 = blockIdx.y << 6;   // 16 tiles of 64
  const int tid = threadIdx.x;
#pragma unroll
  for (int s = 0; s < 2; ++s) {
    int u = s * 256 + tid;
    int r = u >> 3, c = (u & 7) << 3;
    *(f16x8*)&t[r * 72 + c] = *(const f16x8*)(vb + (bh * 1024 + n0 + r) * 64 + c);
  }
  __syncthreads();
#pragma unroll
  for (int s = 0; s < 2; ++s) {
    int u = s * 256 + tid;
    int d = u >> 3, c = (u & 7) << 3;
    f16x8 o;
#pragma unroll
    for (int e = 0; e < 8; ++e) o[e] = t[(c + e) * 72 + d];
    *(f16x8*)(vt + (bh * 64 + d) * 1024 + n0 + c) = o;
  }
}

// ---------------------------------------------------------------- fused attention v7
// block = 256 thr (4 waves) handles (b, 16 query rows).  Wave w owns j-quarter
// jw=w*16 of each 64-j tile for ALL 12 heads.
// KEY CHANGE vs v6: v6's K-tile register prefetch was SPILLED — the kernel uses
// dynamic LDS, so the compiler couldn't see that LDS caps occupancy at 2 waves/
// SIMD and budgeted VGPRs for 4 waves/SIMD (cap 128; kr[12][2]=96 went to
// scratch: WRITE_SIZE 24.6->58.4MB, FETCH 37->64MB, dur +90us).
// __attribute__((amdgpu_waves_per_eu(2,2))) pins the budget to 256 VGPR/wave —
// matching the LDS-forced occupancy — so the cross-iteration pipeline actually
// lives in registers:
//   computeS(kr_j0) -> issue kr <- K(j0+64) -> t-loop (+PV) compute
// Next tile's 24 K loads fly under ~2k cycles of mix/softmax/PV work instead of
// draining serially at the top of each iteration.  S-reads batched 8-at-a-time
// (half-tiles) to bound liveness ~250 VGPR; PV vt loads 2-deep rotated with the
// first issued BEFORE the Pm barrier (independent of Pm).
// Everything else identical: Q in LDS (24KB XOR-swizzled), S staged in
// wave-local LDS b64 units (conflict-free), maxless softmax, post-mix
// in-register via MFMA16, Pm exchange XOR-swizzled, 2 barriers per iteration.
__attribute__((amdgpu_waves_per_eu(2, 2))) __global__ __launch_bounds__(256)
void k_attn(
    const f16* __restrict__ qb, const f16* __restrict__ kb, const f16* __restrict__ vt,
    const float* __restrict__ mixp, const float* __restrict__ mixq,
    f16* __restrict__ ob) {
  extern __shared__ f16 smem[];
  f16* Qs   = smem;            // [12][16][64] f16, 16B-unit XOR swizzle (24KB)
  f16* Slds = smem + 12288;    // 4 waves x 3200 f16: [16 j][3 hgrp][16 u][4] + zeros
  f16* Pmb  = smem + 25088;    // [g'][i][16 units][4] f16 (24KB)

  const int tid = threadIdx.x;
  const int bid0 = blockIdx.x;
  const int xcd = bid0 & 7, idx = bid0 >> 3;
  const int b = ((idx >> 6) << 3) | xcd;   // one b per XCD at a time (L2-resident)
  const int i0 = (idx & 63) << 4;
  const int lane = tid & 63;
  const int w = tid >> 6;
  const int quad = lane >> 4, col = lane & 15;
  const int q4 = quad << 2;
  const int w3 = w * 3;
  const int jw = w << 4;  // wave's j offset within a 64-j iteration
  const f32x4 z4 = {0.f, 0.f, 0.f, 0.f};

  // mix fragments for 16x16x16: lane holds k-slots h = quad*4+e.
  // b_pre : A[m=g=col][k=h]   = mixp[h][g]   (mixp^T)
  // b_post: B[k=g][n=g'=col]  = mixq[g][g']
  f16x4 b_pre, b_post;
#pragma unroll
  for (int e = 0; e < 4; ++e) {
    int hk = q4 + e;
    bool ok = (hk < 12) && (col < 12);
    b_pre[e]  = ok ? (f16)mixp[hk * 12 + col] : (f16)0.f;
    b_post[e] = ok ? (f16)mixq[hk * 12 + col] : (f16)0.f;
  }

  f16* Sw = &Slds[w * 3200];
  // zero block at Sw[3072..3135]: pre-mix k-slots 12..15 (quad==3) read here
  if (lane < 16) {
    f16x4 z; z[0] = (f16)0.f; z[1] = (f16)0.f; z[2] = (f16)0.f; z[3] = (f16)0.f;
    *(f16x4*)&Sw[3072 + lane * 4] = z;
  }

  // stage Q tile -> Qs: Q[h][i][d], d in 8 units of 8 f16, unit stored at u^(i&7)
#pragma unroll
  for (int s = 0; s < 6; ++s) {
    int u = s * 256 + tid;                       // 0..1535
    int h = u >> 7, i = (u >> 3) & 15, uu = u & 7;
    f16x8 q = *(const f16x8*)(qb + ((((b * 12 + h) << 10) + i0 + i) << 6) + uu * 8);
    *(f16x8*)&Qs[(((h << 4) + i) << 6) + ((uu ^ (i & 7)) << 3)] = q;
  }
  __syncthreads();

  // K-tile register buffer (96 VGPR) + loaders / consumers
  f16x8 kr[12][2];
  auto loadK = [&](int j0) {
#pragma unroll
    for (int h = 0; h < 12; ++h) {
      const f16* kbase = kb + ((((b * 12 + h) << 10) + j0 + jw + col) << 6);
      kr[h][0] = *(const f16x8*)(kbase + quad * 8);
      kr[h][1] = *(const f16x8*)(kbase + 32 + quad * 8);
    }
  };
  // QK^T for all 12 heads on this wave's 16 j's from kr; S -> wave-local LDS.
  // unit (j=col, i=q4+r, hgrp) at Sw[j*192 + hg*64 + ((i+j)&15)*4], content h asc.
  auto computeS = [&]() {
#pragma unroll
    for (int hg = 0; hg < 3; ++hg) {
      f32x4 s4[4];
#pragma unroll
      for (int e = 0; e < 4; ++e) {
        int h = hg * 4 + e;
        f16x8 q0 = *(const f16x8*)&Qs[(((h << 4) + col) << 6) +
                                      ((quad ^ (col & 7)) << 3)];
        f16x8 q1 = *(const f16x8*)&Qs[(((h << 4) + col) << 6) +
                                      (((4 + quad) ^ (col & 7)) << 3)];
        f32x4 a = MFMA(q0, kr[h][0], z4);
        s4[e] = MFMA(q1, kr[h][1], a);
      }
#pragma unroll
      for (int r = 0; r < 4; ++r) {
        f16x4 p;
        p[0] = (f16)s4[0][r]; p[1] = (f16)s4[1][r];
        p[2] = (f16)s4[2][r]; p[3] = (f16)s4[3][r];
        *(f16x4*)&Sw[col * 192 + hg * 64 + ((q4 + r + col) & 15) * 4] = p;
      }
    }
  };
  // pre-mix B-frag read address: k-slot group = quad (hgrp), or zero block
  auto sread = [&](int t) -> f16x4 {
    int zi = (quad < 3) ? (t * 192 + quad * 64 + ((col + t) & 15) * 4)
                        : (3072 + ((col + t) & 15) * 4);
    return *(const f16x4*)&Sw[zi];
  };

  // ---------------- phase 1: denominators l per (g,i), fully per-lane, 0 barriers
  float l_run[4] = {0.f, 0.f, 0.f, 0.f};
  loadK(0);
  for (int j0 = 0; j0 < 1024; j0 += 64) {
    computeS();
    if (j0 + 64 < 1024) loadK(j0 + 64);   // next K tile flies under the t-loop
#pragma unroll
    for (int hf = 0; hf < 2; ++hf) {
      f16x4 sB[8];
#pragma unroll
      for (int t = 0; t < 8; ++t) sB[t] = sread(hf * 8 + t);
#pragma unroll
      for (int t = 0; t < 8; ++t) {
        f32x4 d1 = MFMA16(b_pre, sB[t], z4);
#pragma unroll
        for (int r = 0; r < 4; ++r) l_run[r] += __expf(d1[r]);
      }
    }
  }
  // merge partial l across the 4 waves (disjoint j quarters)
  float* Lb = (float*)Pmb;  // [w][g(16)][i(16)] overlay, phase-boundary only
#pragma unroll
  for (int r = 0; r < 4; ++r) Lb[(w * 16 + q4 + r) * 16 + col] = l_run[r];
  __syncthreads();
  float il[4];
#pragma unroll
  for (int r = 0; r < 4; ++r) {
    float s = 0.f;
#pragma unroll
    for (int ww = 0; ww < 4; ++ww) s += Lb[(ww * 16 + q4 + r) * 16 + col];
    il[r] = 1.f / s;
  }
  __syncthreads();  // Lb region handed back to Pm

  // ---------------- phase 2: recompute d1, P, post-mix, PV
  f32x4 oa[3][4];
#pragma unroll
  for (int g = 0; g < 3; ++g)
#pragma unroll
    for (int dc = 0; dc < 4; ++dc) oa[g][dc] = z4;

  f16x8 vrA[2][4], vrB[2][4];
  auto loadV = [&](f16x8 (&vr)[2][4], int gp, int j0) {
#pragma unroll
    for (int jh = 0; jh < 2; ++jh)
#pragma unroll
      for (int dc = 0; dc < 4; ++dc)
        vr[jh][dc] = *(const f16x8*)(vt + ((((b * 12 + gp) << 6) + dc * 16 + col) << 10) +
                                     j0 + jh * 32 + quad * 8);
  };
  auto pvHead = [&](f16x8 (&vr)[2][4], int gg) {
    int gp = w3 + gg;
    int k4r = (gp + col) & 15;
#pragma unroll
    for (int jh = 0; jh < 2; ++jh) {
      int ub = (jh * 4 + quad) * 2;
      f16x4 lo = *(const f16x4*)&Pmb[(((gp << 4) + col) * 16 + (ub ^ k4r)) * 4];
      f16x4 hi = *(const f16x4*)&Pmb[(((gp << 4) + col) * 16 + ((ub + 1) ^ k4r)) * 4];
      f16x8 aP = __builtin_shufflevector(lo, hi, 0, 1, 2, 3, 4, 5, 6, 7);
#pragma unroll
      for (int dc = 0; dc < 4; ++dc)
        oa[gg][dc] = MFMA(aP, vr[jh][dc], oa[gg][dc]);
    }
  };

  loadK(0);
  for (int j0 = 0; j0 < 1024; j0 += 64) {
    computeS();
    if (j0 + 64 < 1024) loadK(j0 + 64);   // next K tile flies under t-loop + PV
#pragma unroll
    for (int hf = 0; hf < 2; ++hf) {
      f16x4 sB[8];
#pragma unroll
      for (int t = 0; t < 8; ++t) sB[t] = sread(hf * 8 + t);
#pragma unroll
      for (int tt = 0; tt < 2; ++tt) {  // Pm flush per 4 tiles
        f16x4 pk[4];
#pragma unroll
        for (int t4 = 0; t4 < 4; ++t4) {
          int t = tt * 4 + t4;
          f32x4 d1 = MFMA16(b_pre, sB[t], z4);
          f16x4 pA;
#pragma unroll
          for (int r = 0; r < 4; ++r) pA[r] = (f16)(__expf(d1[r]) * il[r]);
          f32x4 d2 = MFMA16(pA, b_post, z4);  // lane: (i=q4+r, g'=col, j=t)
#pragma unroll
          for (int r = 0; r < 4; ++r) pk[r][t4] = (f16)d2[r];
        }
        // flush unit (w*4 + hf*2+tt) of row (g'=col, i=q4+r), XOR-swizzled
        if (col < 12) {
          int ttg = hf * 2 + tt;
#pragma unroll
          for (int r = 0; r < 4; ++r) {
            int k4 = (col + q4 + r) & 15;
            *(f16x4*)&Pmb[(((col << 4) + q4 + r) * 16 + ((w * 4 + ttg) ^ k4)) * 4] = pk[r];
          }
        }
      }
    }
    loadV(vrA, w3 + 0, j0);   // independent of Pm: issue before the barrier
    __syncthreads();  // Pm complete (all 64 j from all waves)
    // PV: wave w owns heads 3w..3w+2; vt loads 2-deep rotated across heads
    loadV(vrB, w3 + 1, j0);
    pvHead(vrA, 0);
    loadV(vrA, w3 + 2, j0);
    pvHead(vrB, 1);
    pvHead(vrA, 2);
    __syncthreads();  // Pm consumed before next iteration overwrites
  }

  // epilogue: O (C-layout: row=q4+r = i, col = d) -> obuf [b][n][768]
#pragma unroll
  for (int gg = 0; gg < 3; ++gg) {
    int gp = w3 + gg;
#pragma unroll
    for (int dc = 0; dc < 4; ++dc)
#pragma unroll
      for (int r = 0; r < 4; ++r)
        ob[((b << 10) + i0 + q4 + r) * 768 + gp * 64 + dc * 16 + col] =
            (f16)oa[gg][dc][r];
  }
}

// ---------------------------------------------------------------- output GEMM
__global__ __launch_bounds__(256) void k_gemm_out(const f16* __restrict__ A,
                                                  const f16* __restrict__ Bt,
                                                  const float* __restrict__ bias,
                                                  float* __restrict__ out) {
  __shared__ f16 As[128 * 72];
  __shared__ f16 Bs[128 * 72];
  const int tid = threadIdx.x;
  const int m0 = blockIdx.y << 7;
  const int n0 = blockIdx.x << 7;
  const int lane = tid & 63, w = tid >> 6;
  const int quad = lane >> 4, col = lane & 15;
  const int wm = (w >> 1) << 6, wn = (w & 1) << 6;
  const f32x4 z4 = {0.f, 0.f, 0.f, 0.f};
  f32x4 acc[4][4];
#pragma unroll
  for (int i = 0; i < 4; ++i)
#pragma unroll
    for (int j = 0; j < 4; ++j) acc[i][j] = z4;

  for (int k0 = 0; k0 < 768; k0 += 64) {
#pragma unroll
    for (int s = 0; s < 4; ++s) {
      int u = s * 256 + tid;
      int row = u >> 3, seg = (u & 7) << 3;
      *(f16x8*)&As[row * 72 + seg] = *(const f16x8*)(A + (m0 + row) * 768 + k0 + seg);
      *(f16x8*)&Bs[row * 72 + seg] = *(const f16x8*)(Bt + (n0 + row) * 768 + k0 + seg);
    }
    __syncthreads();
#pragma unroll
    for (int kk = 0; kk < 64; kk += 32) {
      f16x8 af[4], bf[4];
#pragma unroll
      for (int ic = 0; ic < 4; ++ic)
        af[ic] = *(f16x8*)&As[(wm + ic * 16 + col) * 72 + kk + quad * 8];
#pragma unroll
      for (int jc = 0; jc < 4; ++jc)
        bf[jc] = *(f16x8*)&Bs[(wn + jc * 16 + col) * 72 + kk + quad * 8];
#pragma unroll
      for (int ic = 0; ic < 4; ++ic)
#pragma unroll
        for (int jc = 0; jc < 4; ++jc) acc[ic][jc] = MFMA(af[ic], bf[jc], acc[ic][jc]);
    }
    __syncthreads();
  }
#pragma unroll
  for (int jc = 0; jc < 4; ++jc) {
    int gn = n0 + wn + jc * 16 + col;
    float bv = bias[gn];
#pragma unroll
    for (int ic = 0; ic < 4; ++ic)
#pragma unroll
      for (int r = 0; r < 4; ++r) {
        int gm = m0 + wm + ic * 16 + (quad << 2) + r;
        out[gm * 768 + gn] = acc[ic][jc][r] + bv;
      }
  }
}

// ---------------------------------------------------------------- launcher
extern "C" void kernel_launch(void* const* d_in, const int* in_sizes, int n_in,
                              void* d_out, int out_size, void* d_ws, size_t ws_size,
                              hipStream_t stream) {
  const float* x    = (const float*)d_in[0];
  const float* Wq   = (const float*)d_in[1];
  const float* Wkv  = (const float*)d_in[2];
  const float* mixp = (const float*)d_in[3];
  const float* mixq = (const float*)d_in[4];
  const float* Wo   = (const float*)d_in[5];
  const float* bo   = (const float*)d_in[6];
  float* out = (float*)d_out;

  char* ws = (char*)d_ws;
  f16* xb  = (f16*)(ws);
  f16* Wt  = (f16*)(ws + 25165824);
  f16* WoT = (f16*)(ws + 28704768);
  f16* qb  = (f16*)(ws + 29884416);
  f16* kb  = (f16*)(ws + 55050240);
  f16* vb  = (f16*)(ws + 80216064);
  f16* vt  = xb;   // xb dead after k_gemm_qkv
  f16* obuf = vb;  // vb dead after k_transpose_v

  k_cast_x<<<dim3(6144), dim3(256), 0, stream>>>(x, xb);
  k_prep_w<<<dim3(9216), dim3(256), 0, stream>>>(Wq, Wkv, Wo, Wt, WoT);
  k_gemm_qkv<<<dim3(18, 128), dim3(256), 0, stream>>>(xb, Wt, qb, kb, vb);
  k_transpose_v<<<dim3(192, 16), dim3(256), 0, stream>>>(vb, vt);
  k_attn<<<dim3(1024), dim3(256), 74752, stream>>>(qb, kb, vt, mixp, mixq, obuf);
  k_gemm_out<<<dim3(6, 128), dim3(256), 0, stream>>>(obuf, WoT, bo, out);
}

// Round 9
// 812.133 us; speedup vs baseline: 1.0693x; 1.0584x over previous
//
#include <hip/hip_runtime.h>

// Talking-heads attention, fully fused two-phase flash-style implementation.
// b=16, n=1024, dim=768, h=12, d=64.  All staged tensors fp16, MFMA 16x16x32 f16.
//
// Pipeline:
//  1. k_cast_x     : x (f32) -> xb (f16)
//  2. k_prep_w     : Wt = [Wq*SCALE | Wkv]^T (f16, N-major), WoT = Wo^T (f16)
//  3. k_gemm_qkv   : [q|k|v] = xb @ Wt, scattered to per-head [b][h][n][64] f16
//  4. k_transpose_v: vt[b][h][d][n] (so PV B-fragments are contiguous)
//  5. k_attn       : per (b, 16-row i-tile), see header comment at the kernel
//  6. k_gemm_out   : out = obuf @ WoT + bo (f32)
//
// Workspace layout (bytes), total 105,381,888:
//   xb   @ 0          (25,165,824)   -- reused as vt after gemm_qkv
//   Wt   @ 25165824   ( 3,538,944)
//   WoT  @ 28704768   ( 1,179,648)
//   qb   @ 29884416   (25,165,824)
//   kb   @ 55050240   (25,165,824)
//   vb   @ 80216064   (25,165,824)   -- reused as obuf after transpose

typedef _Float16 f16;
typedef _Float16 f16x8 __attribute__((ext_vector_type(8)));
typedef _Float16 f16x4 __attribute__((ext_vector_type(4)));
typedef float f32x4 __attribute__((ext_vector_type(4)));
typedef float fv4 __attribute__((ext_vector_type(4)));

#define MFMA(a, b, c) __builtin_amdgcn_mfma_f32_16x16x32_f16(a, b, c, 0, 0, 0)
#define MFMA16(a, b, c) __builtin_amdgcn_mfma_f32_16x16x16f16(a, b, c, 0, 0, 0)

// ---------------------------------------------------------------- cast x -> f16
__global__ __launch_bounds__(256) void k_cast_x(const float* __restrict__ x,
                                                f16* __restrict__ xb) {
  int idx = (blockIdx.x * 256 + threadIdx.x) * 8;
  fv4 a = *(const fv4*)(x + idx);
  fv4 b = *(const fv4*)(x + idx + 4);
  f16x8 o;
  o[0] = (f16)a[0]; o[1] = (f16)a[1]; o[2] = (f16)a[2]; o[3] = (f16)a[3];
  o[4] = (f16)b[0]; o[5] = (f16)b[1]; o[6] = (f16)b[2]; o[7] = (f16)b[3];
  *(f16x8*)(xb + idx) = o;
}

// ------------------------------------------- weights: transpose + cast (+scale q)
__global__ __launch_bounds__(256) void k_prep_w(const float* __restrict__ Wq,
                                                const float* __restrict__ Wkv,
                                                const float* __restrict__ Wo,
                                                f16* __restrict__ Wt,
                                                f16* __restrict__ WoT) {
  int idx = blockIdx.x * 256 + threadIdx.x;
  if (idx < 2304 * 768) {
    int n = idx / 768, k = idx % 768;
    float v = (n < 768) ? Wq[k * 768 + n] * 0.125f   // SCALE = 64^-0.5 folded here
                        : Wkv[k * 1536 + (n - 768)];
    Wt[idx] = (f16)v;
  } else {
    int id2 = idx - 2304 * 768;
    int n = id2 / 768, k = id2 % 768;
    WoT[id2] = (f16)Wo[k * 768 + n];
  }
}

// ---------------------------------------------------------------- QKV projection
__global__ __launch_bounds__(256) void k_gemm_qkv(const f16* __restrict__ A,
                                                  const f16* __restrict__ Bt,
                                                  f16* __restrict__ qb,
                                                  f16* __restrict__ kb,
                                                  f16* __restrict__ vb) {
  __shared__ f16 As[128 * 72];  // +8 pad: conflict-free b128 frag reads
  __shared__ f16 Bs[128 * 72];
  const int tid = threadIdx.x;
  const int m0 = blockIdx.y << 7;
  const int n0 = blockIdx.x << 7;
  const int lane = tid & 63, w = tid >> 6;
  const int quad = lane >> 4, col = lane & 15;
  const int wm = (w >> 1) << 6, wn = (w & 1) << 6;
  const f32x4 z4 = {0.f, 0.f, 0.f, 0.f};
  f32x4 acc[4][4];
#pragma unroll
  for (int i = 0; i < 4; ++i)
#pragma unroll
    for (int j = 0; j < 4; ++j) acc[i][j] = z4;

  for (int k0 = 0; k0 < 768; k0 += 64) {
#pragma unroll
    for (int s = 0; s < 4; ++s) {
      int u = s * 256 + tid;
      int row = u >> 3, seg = (u & 7) << 3;
      *(f16x8*)&As[row * 72 + seg] = *(const f16x8*)(A + (m0 + row) * 768 + k0 + seg);
      *(f16x8*)&Bs[row * 72 + seg] = *(const f16x8*)(Bt + (n0 + row) * 768 + k0 + seg);
    }
    __syncthreads();
#pragma unroll
    for (int kk = 0; kk < 64; kk += 32) {
      f16x8 af[4], bf[4];
#pragma unroll
      for (int ic = 0; ic < 4; ++ic)
        af[ic] = *(f16x8*)&As[(wm + ic * 16 + col) * 72 + kk + quad * 8];
#pragma unroll
      for (int jc = 0; jc < 4; ++jc)
        bf[jc] = *(f16x8*)&Bs[(wn + jc * 16 + col) * 72 + kk + quad * 8];
#pragma unroll
      for (int ic = 0; ic < 4; ++ic)
#pragma unroll
        for (int jc = 0; jc < 4; ++jc) acc[ic][jc] = MFMA(af[ic], bf[jc], acc[ic][jc]);
    }
    __syncthreads();
  }
  // epilogue: scatter to per-head q/k/v layouts
#pragma unroll
  for (int jc = 0; jc < 4; ++jc) {
    int gn = n0 + wn + jc * 16 + col;
#pragma unroll
    for (int ic = 0; ic < 4; ++ic)
#pragma unroll
      for (int r = 0; r < 4; ++r) {
        int gm = m0 + wm + ic * 16 + (quad << 2) + r;
        int b = gm >> 10, i = gm & 1023;
        f16 v = (f16)acc[ic][jc][r];
        if (gn < 768) {
          int h = gn >> 6, dd = gn & 63;
          qb[(((b * 12 + h) << 10) + i) * 64 + dd] = v;
        } else if (gn < 1536) {
          int t = gn - 768; int h = t >> 6, dd = t & 63;
          kb[(((b * 12 + h) << 10) + i) * 64 + dd] = v;
        } else {
          int t = gn - 1536; int h = t >> 6, dd = t & 63;
          vb[(((b * 12 + h) << 10) + i) * 64 + dd] = v;
        }
      }
  }
}

// ---------------------------------------------------------------- V transpose
__global__ __launch_bounds__(256) void k_transpose_v(const f16* __restrict__ vb,
                                                     f16* __restrict__ vt) {
  __shared__ f16 t[64 * 72];
  const int bh = blockIdx.x;        // 0..191
  const int n0 = blockIdx.y << 6;   // 16 tiles of 64
  const int tid = threadIdx.x;
#pragma unroll
  for (int s = 0; s < 2; ++s) {
    int u = s * 256 + tid;
    int r = u >> 3, c = (u & 7) << 3;
    *(f16x8*)&t[r * 72 + c] = *(const f16x8*)(vb + (bh * 1024 + n0 + r) * 64 + c);
  }
  __syncthreads();
#pragma unroll
  for (int s = 0; s < 2; ++s) {
    int u = s * 256 + tid;
    int d = u >> 3, c = (u & 7) << 3;
    f16x8 o;
#pragma unroll
    for (int e = 0; e < 8; ++e) o[e] = t[(c + e) * 72 + d];
    *(f16x8*)(vt + (bh * 64 + d) * 1024 + n0 + c) = o;
  }
}

// ---------------------------------------------------------------- fused attention v8
// block = 512 thr (8 waves) handles (b, 16 query rows).  32-j tiles.
// Wave w = (hh = w>>1 in 0..3, jh = w&1): computes S for 3 heads {3hh..3hh+2}
// over j-half jh (16 j) of the tile.  RATIONALE vs v5 (566us, measured ~80%
// per-wave stall with only 2 waves/SIMD): this split cuts per-wave state so Q
// fits in 24 VGPRs (no Qs LDS) and shrinks LDS to 56KB double-buffered ->
// 16 waves/CU (4/SIMD) = 2x latency hiding, with the VGPR budget (128 @
// launch_bounds(512,4)) ALIGNED to the LDS-permitted occupancy (no spills).
//   S units are 3 heads + 0-pad (f16x4); pre-mix k-slot 4q+e -> head 3q+e.
//   S exchange: Slds[32 j][4 hgrp][16 units][4], unit swizzle (i+j)&15,
//   double-buffered (16KB x2) -> 1 barrier per phase-1 iteration.
//   t-loop: 8 waves x 4 t = 32 j; per-lane maxless softmax stats as in v5.
//   Pm[12 g'][16 i][8 units][4] (XOR key (g'+i)&7), double-buffered (12KB x2)
//   -> 2 barriers per phase-2 iteration.  PV: 24 (head,d-half) units / 8 waves
//   = 3 each; V loads issued right after computeS (hide under t-loop).
__global__ __launch_bounds__(512, 4) void k_attn(
    const f16* __restrict__ qb, const f16* __restrict__ kb, const f16* __restrict__ vt,
    const float* __restrict__ mixp, const float* __restrict__ mixq,
    f16* __restrict__ ob) {
  extern __shared__ f16 smem[];
  // smem: Sbuf[2] @ 0, 8192   (each [32][4][16][4] f16 = 16KB)
  //       Pbuf[2] @ 16384, 22528 (each [12][16][8][4] f16 = 12KB)  total 56KB

  const int tid = threadIdx.x;
  const int bid0 = blockIdx.x;
  const int xcd = bid0 & 7, idx = bid0 >> 3;
  const int b = ((idx >> 6) << 3) | xcd;   // one b per XCD at a time (L2-resident)
  const int i0 = (idx & 63) << 4;
  const int lane = tid & 63;
  const int w = tid >> 6;                  // 0..7
  const int quad = lane >> 4, col = lane & 15;
  const int q4 = quad << 2;
  const int hh = w >> 1;                   // head-group 0..3 (3 heads each)
  const int jh = w & 1;                    // j-half of the 32-j tile
  const f32x4 z4 = {0.f, 0.f, 0.f, 0.f};

  // mix fragments for 16x16x16.
  // b_pre : A[m=g=col][k=4*quad+e] = mixp[head(3*quad+e)][g]  (slot e=3 is pad)
  // b_post: B[k=g=q4+e][n=g'=col]  = mixq[g][g']
  f16x4 b_pre, b_post;
#pragma unroll
  for (int e = 0; e < 4; ++e) {
    b_pre[e]  = (e < 3 && col < 12) ? (f16)mixp[(3 * quad + e) * 12 + col] : (f16)0.f;
    int hk = q4 + e;
    b_post[e] = (hk < 12 && col < 12) ? (f16)mixq[hk * 12 + col] : (f16)0.f;
  }

  // Q fragments in registers: 3 heads x 2 k-chunks (24 VGPR)
  f16x8 qf[3][2];
#pragma unroll
  for (int e = 0; e < 3; ++e)
#pragma unroll
    for (int kc = 0; kc < 2; ++kc)
      qf[e][kc] = *(const f16x8*)(qb + ((((b * 12 + 3 * hh + e) << 10) + i0 + col) << 6) +
                                  kc * 32 + quad * 8);

  // computeS: QK^T for this wave's 3 heads x 16 j -> S units in Sw.
  // unit (j = 16*jh+col, i = q4+r, hgrp = hh) at Sw[(j*4+hh)*16 + ((i+j)&15)],
  // content = heads {3hh, 3hh+1, 3hh+2, pad0}.
  auto computeS = [&](int j0, f16* Sw) {
    f16x8 kr[3][2];
#pragma unroll
    for (int e = 0; e < 3; ++e) {
      const f16* kbase =
          kb + ((((b * 12 + 3 * hh + e) << 10) + j0 + jh * 16 + col) << 6);
      kr[e][0] = *(const f16x8*)(kbase + quad * 8);
      kr[e][1] = *(const f16x8*)(kbase + 32 + quad * 8);
    }
    f32x4 s4[3];
#pragma unroll
    for (int e = 0; e < 3; ++e) {
      f32x4 a = MFMA(qf[e][0], kr[e][0], z4);
      s4[e] = MFMA(qf[e][1], kr[e][1], a);
    }
    int jj = jh * 16 + col;
#pragma unroll
    for (int r = 0; r < 4; ++r) {
      f16x4 p;
      p[0] = (f16)s4[0][r]; p[1] = (f16)s4[1][r]; p[2] = (f16)s4[2][r];
      p[3] = (f16)0.f;
      *(f16x4*)&Sw[((jj * 4 + hh) * 16 + ((q4 + r + col) & 15)) * 4] = p;
    }
  };
  // pre-mix B-frag read: lane (quad,col) reads [t][hgrp=quad][(col+t)&15]
  auto sread = [&](int t, const f16* Sw) -> f16x4 {
    return *(const f16x4*)&Sw[((t * 4 + quad) * 16 + ((col + t) & 15)) * 4];
  };

  // ---------------- phase 1: denominators l per (g,i); 1 barrier/iter (S dbuf)
  float l_run[4] = {0.f, 0.f, 0.f, 0.f};
  for (int n = 0; n < 32; ++n) {
    f16* Sw = smem + (n & 1) * 8192;
    computeS(n * 32, Sw);
    __syncthreads();
    f16x4 sB[4];
#pragma unroll
    for (int t4 = 0; t4 < 4; ++t4) sB[t4] = sread(w * 4 + t4, Sw);
#pragma unroll
    for (int t4 = 0; t4 < 4; ++t4) {
      f32x4 d1 = MFMA16(b_pre, sB[t4], z4);
#pragma unroll
      for (int r = 0; r < 4; ++r) l_run[r] += __expf(d1[r]);
    }
  }
  // merge partial l across the 8 waves
  float* Lb = (float*)(smem + 16384);  // overlays Pbuf[0], phase boundary only
#pragma unroll
  for (int r = 0; r < 4; ++r) Lb[(w * 16 + q4 + r) * 16 + col] = l_run[r];
  __syncthreads();
  float il[4];
#pragma unroll
  for (int r = 0; r < 4; ++r) {
    float s = 0.f;
#pragma unroll
    for (int ww = 0; ww < 8; ++ww) s += Lb[(ww * 16 + q4 + r) * 16 + col];
    il[r] = 1.f / s;
  }
  __syncthreads();  // Lb handed back to Pm

  // ---------------- phase 2: recompute S, P=exp*il, post-mix, PV
  f32x4 oa[3][2];
#pragma unroll
  for (int u3 = 0; u3 < 3; ++u3) { oa[u3][0] = z4; oa[u3][1] = z4; }

  for (int n = 0; n < 32; ++n) {
    int j0 = n * 32;
    f16* Sw = smem + (n & 1) * 8192;
    f16* Pm = smem + 16384 + (n & 1) * 6144;
    computeS(j0, Sw);
    // V loads early (independent of S/Pm): 3 (head,d-half) units x 2 dc
    f16x8 vr[3][2];
#pragma unroll
    for (int u3 = 0; u3 < 3; ++u3) {
      int u = w * 3 + u3, gp = u >> 1, dh = u & 1;
#pragma unroll
      for (int dc = 0; dc < 2; ++dc)
        vr[u3][dc] = *(const f16x8*)(vt +
            ((((b * 12 + gp) << 6) + dh * 32 + dc * 16 + col) << 10) + j0 + quad * 8);
    }
    __syncthreads();  // S complete
    f16x4 sB[4];
#pragma unroll
    for (int t4 = 0; t4 < 4; ++t4) sB[t4] = sread(w * 4 + t4, Sw);
    f16x4 pk[4];
#pragma unroll
    for (int t4 = 0; t4 < 4; ++t4) {
      f32x4 d1 = MFMA16(b_pre, sB[t4], z4);
      f16x4 pA;
#pragma unroll
      for (int r = 0; r < 4; ++r) pA[r] = (f16)(__expf(d1[r]) * il[r]);
      f32x4 d2 = MFMA16(pA, b_post, z4);  // lane: (i=q4+r, g'=col, j=w*4+t4)
#pragma unroll
      for (int r = 0; r < 4; ++r) pk[r][t4] = (f16)d2[r];
    }
    // Pm write: unit w of row (g'=col, i=q4+r), XOR key (g'+i)&7
    if (col < 12) {
#pragma unroll
      for (int r = 0; r < 4; ++r) {
        int k4 = (col + q4 + r) & 7;
        *(f16x4*)&Pm[(((col << 4) + q4 + r) * 8 + (w ^ k4)) * 4] = pk[r];
      }
    }
    __syncthreads();  // Pm complete
    // PV: wave owns units 3w..3w+2 of the 24 (head, d-half) pairs
#pragma unroll
    for (int u3 = 0; u3 < 3; ++u3) {
      int u = w * 3 + u3, gp = u >> 1;
      int k4r = (gp + col) & 7;
      f16x4 lo = *(const f16x4*)&Pm[(((gp << 4) + col) * 8 + ((quad * 2) ^ k4r)) * 4];
      f16x4 hi = *(const f16x4*)&Pm[(((gp << 4) + col) * 8 + ((quad * 2 + 1) ^ k4r)) * 4];
      f16x8 aP = __builtin_shufflevector(lo, hi, 0, 1, 2, 3, 4, 5, 6, 7);
#pragma unroll
      for (int dc = 0; dc < 2; ++dc)
        oa[u3][dc] = MFMA(aP, vr[u3][dc], oa[u3][dc]);
    }
  }

  // epilogue: O (C-layout: row=q4+r = i, col -> d) -> obuf [b][n][768]
#pragma unroll
  for (int u3 = 0; u3 < 3; ++u3) {
    int u = w * 3 + u3, gp = u >> 1, dh = u & 1;
#pragma unroll
    for (int dc = 0; dc < 2; ++dc)
#pragma unroll
      for (int r = 0; r < 4; ++r)
        ob[((b << 10) + i0 + q4 + r) * 768 + gp * 64 + dh * 32 + dc * 16 + col] =
            (f16)oa[u3][dc][r];
  }
}

// ---------------------------------------------------------------- output GEMM
__global__ __launch_bounds__(256) void k_gemm_out(const f16* __restrict__ A,
                                                  const f16* __restrict__ Bt,
                                                  const float* __restrict__ bias,
                                                  float* __restrict__ out) {
  __shared__ f16 As[128 * 72];
  __shared__ f16 Bs[128 * 72];
  const int tid = threadIdx.x;
  const int m0 = blockIdx.y << 7;
  const int n0 = blockIdx.x << 7;
  const int lane = tid & 63, w = tid >> 6;
  const int quad = lane >> 4, col = lane & 15;
  const int wm = (w >> 1) << 6, wn = (w & 1) << 6;
  const f32x4 z4 = {0.f, 0.f, 0.f, 0.f};
  f32x4 acc[4][4];
#pragma unroll
  for (int i = 0; i < 4; ++i)
#pragma unroll
    for (int j = 0; j < 4; ++j) acc[i][j] = z4;

  for (int k0 = 0; k0 < 768; k0 += 64) {
#pragma unroll
    for (int s = 0; s < 4; ++s) {
      int u = s * 256 + tid;
      int row = u >> 3, seg = (u & 7) << 3;
      *(f16x8*)&As[row * 72 + seg] = *(const f16x8*)(A + (m0 + row) * 768 + k0 + seg);
      *(f16x8*)&Bs[row * 72 + seg] = *(const f16x8*)(Bt + (n0 + row) * 768 + k0 + seg);
    }
    __syncthreads();
#pragma unroll
    for (int kk = 0; kk < 64; kk += 32) {
      f16x8 af[4], bf[4];
#pragma unroll
      for (int ic = 0; ic < 4; ++ic)
        af[ic] = *(f16x8*)&As[(wm + ic * 16 + col) * 72 + kk + quad * 8];
#pragma unroll
      for (int jc = 0; jc < 4; ++jc)
        bf[jc] = *(f16x8*)&Bs[(wn + jc * 16 + col) * 72 + kk + quad * 8];
#pragma unroll
      for (int ic = 0; ic < 4; ++ic)
#pragma unroll
        for (int jc = 0; jc < 4; ++jc) acc[ic][jc] = MFMA(af[ic], bf[jc], acc[ic][jc]);
    }
    __syncthreads();
  }
#pragma unroll
  for (int jc = 0; jc < 4; ++jc) {
    int gn = n0 + wn + jc * 16 + col;
    float bv = bias[gn];
#pragma unroll
    for (int ic = 0; ic < 4; ++ic)
#pragma unroll
      for (int r = 0; r < 4; ++r) {
        int gm = m0 + wm + ic * 16 + (quad << 2) + r;
        out[gm * 768 + gn] = acc[ic][jc][r] + bv;
      }
  }
}

// ---------------------------------------------------------------- launcher
extern "C" void kernel_launch(void* const* d_in, const int* in_sizes, int n_in,
                              void* d_out, int out_size, void* d_ws, size_t ws_size,
                              hipStream_t stream) {
  const float* x    = (const float*)d_in[0];
  const float* Wq   = (const float*)d_in[1];
  const float* Wkv  = (const float*)d_in[2];
  const float* mixp = (const float*)d_in[3];
  const float* mixq = (const float*)d_in[4];
  const float* Wo   = (const float*)d_in[5];
  const float* bo   = (const float*)d_in[6];
  float* out = (float*)d_out;

  char* ws = (char*)d_ws;
  f16* xb  = (f16*)(ws);
  f16* Wt  = (f16*)(ws + 25165824);
  f16* WoT = (f16*)(ws + 28704768);
  f16* qb  = (f16*)(ws + 29884416);
  f16* kb  = (f16*)(ws + 55050240);
  f16* vb  = (f16*)(ws + 80216064);
  f16* vt  = xb;   // xb dead after k_gemm_qkv
  f16* obuf = vb;  // vb dead after k_transpose_v

  k_cast_x<<<dim3(6144), dim3(256), 0, stream>>>(x, xb);
  k_prep_w<<<dim3(9216), dim3(256), 0, stream>>>(Wq, Wkv, Wo, Wt, WoT);
  k_gemm_qkv<<<dim3(18, 128), dim3(256), 0, stream>>>(xb, Wt, qb, kb, vb);
  k_transpose_v<<<dim3(192, 16), dim3(256), 0, stream>>>(vb, vt);
  k_attn<<<dim3(1024), dim3(512), 57344, stream>>>(qb, kb, vt, mixp, mixq, obuf);
  k_gemm_out<<<dim3(6, 128), dim3(256), 0, stream>>>(obuf, WoT, bo, out);
}

// Round 11
// 810.768 us; speedup vs baseline: 1.0711x; 1.0017x over previous
//
#include <hip/hip_runtime.h>

// Talking-heads attention, fully fused two-phase flash-style implementation.
// b=16, n=1024, dim=768, h=12, d=64.  All staged tensors fp16, MFMA 16x16x32 f16.
//
// Pipeline:
//  1. k_cast_x     : x (f32) -> xb (f16)
//  2. k_prep_w     : Wt = [Wq*SCALE | Wkv]^T (f16, N-major), WoT = Wo^T (f16)
//  3. k_gemm_qkv   : [q|k|v] = xb @ Wt, scattered to per-head [b][h][n][64] f16
//  4. k_transpose_v: vt[b][h][d][n] (so PV B-fragments are contiguous)
//  5. k_attn       : per (b, 16-row i-tile), see header comment at the kernel
//  6. k_gemm_out   : out = obuf @ WoT + bo (f32)
//
// Workspace layout (bytes), total 105,381,888:
//   xb   @ 0          (25,165,824)   -- reused as vt after gemm_qkv
//   Wt   @ 25165824   ( 3,538,944)
//   WoT  @ 28704768   ( 1,179,648)
//   qb   @ 29884416   (25,165,824)
//   kb   @ 55050240   (25,165,824)
//   vb   @ 80216064   (25,165,824)   -- reused as obuf after transpose

typedef _Float16 f16;
typedef _Float16 f16x8 __attribute__((ext_vector_type(8)));
typedef _Float16 f16x4 __attribute__((ext_vector_type(4)));
typedef float f32x4 __attribute__((ext_vector_type(4)));
typedef float fv4 __attribute__((ext_vector_type(4)));

#define MFMA(a, b, c) __builtin_amdgcn_mfma_f32_16x16x32_f16(a, b, c, 0, 0, 0)
#define MFMA16(a, b, c) __builtin_amdgcn_mfma_f32_16x16x16f16(a, b, c, 0, 0, 0)

// ---------------------------------------------------------------- cast x -> f16
__global__ __launch_bounds__(256) void k_cast_x(const float* __restrict__ x,
                                                f16* __restrict__ xb) {
  int idx = (blockIdx.x * 256 + threadIdx.x) * 8;
  fv4 a = *(const fv4*)(x + idx);
  fv4 b = *(const fv4*)(x + idx + 4);
  f16x8 o;
  o[0] = (f16)a[0]; o[1] = (f16)a[1]; o[2] = (f16)a[2]; o[3] = (f16)a[3];
  o[4] = (f16)b[0]; o[5] = (f16)b[1]; o[6] = (f16)b[2]; o[7] = (f16)b[3];
  *(f16x8*)(xb + idx) = o;
}

// ------------------------------------------- weights: transpose + cast (+scale q)
__global__ __launch_bounds__(256) void k_prep_w(const float* __restrict__ Wq,
                                                const float* __restrict__ Wkv,
                                                const float* __restrict__ Wo,
                                                f16* __restrict__ Wt,
                                                f16* __restrict__ WoT) {
  int idx = blockIdx.x * 256 + threadIdx.x;
  if (idx < 2304 * 768) {
    int n = idx / 768, k = idx % 768;
    float v = (n < 768) ? Wq[k * 768 + n] * 0.125f   // SCALE = 64^-0.5 folded here
                        : Wkv[k * 1536 + (n - 768)];
    Wt[idx] = (f16)v;
  } else {
    int id2 = idx - 2304 * 768;
    int n = id2 / 768, k = id2 % 768;
    WoT[id2] = (f16)Wo[k * 768 + n];
  }
}

// ---------------------------------------------------------------- QKV projection
__global__ __launch_bounds__(256) void k_gemm_qkv(const f16* __restrict__ A,
                                                  const f16* __restrict__ Bt,
                                                  f16* __restrict__ qb,
                                                  f16* __restrict__ kb,
                                                  f16* __restrict__ vb) {
  __shared__ f16 As[128 * 72];  // +8 pad: conflict-free b128 frag reads
  __shared__ f16 Bs[128 * 72];
  const int tid = threadIdx.x;
  const int m0 = blockIdx.y << 7;
  const int n0 = blockIdx.x << 7;
  const int lane = tid & 63, w = tid >> 6;
  const int quad = lane >> 4, col = lane & 15;
  const int wm = (w >> 1) << 6, wn = (w & 1) << 6;
  const f32x4 z4 = {0.f, 0.f, 0.f, 0.f};
  f32x4 acc[4][4];
#pragma unroll
  for (int i = 0; i < 4; ++i)
#pragma unroll
    for (int j = 0; j < 4; ++j) acc[i][j] = z4;

  for (int k0 = 0; k0 < 768; k0 += 64) {
#pragma unroll
    for (int s = 0; s < 4; ++s) {
      int u = s * 256 + tid;
      int row = u >> 3, seg = (u & 7) << 3;
      *(f16x8*)&As[row * 72 + seg] = *(const f16x8*)(A + (m0 + row) * 768 + k0 + seg);
      *(f16x8*)&Bs[row * 72 + seg] = *(const f16x8*)(Bt + (n0 + row) * 768 + k0 + seg);
    }
    __syncthreads();
#pragma unroll
    for (int kk = 0; kk < 64; kk += 32) {
      f16x8 af[4], bf[4];
#pragma unroll
      for (int ic = 0; ic < 4; ++ic)
        af[ic] = *(f16x8*)&As[(wm + ic * 16 + col) * 72 + kk + quad * 8];
#pragma unroll
      for (int jc = 0; jc < 4; ++jc)
        bf[jc] = *(f16x8*)&Bs[(wn + jc * 16 + col) * 72 + kk + quad * 8];
#pragma unroll
      for (int ic = 0; ic < 4; ++ic)
#pragma unroll
        for (int jc = 0; jc < 4; ++jc) acc[ic][jc] = MFMA(af[ic], bf[jc], acc[ic][jc]);
    }
    __syncthreads();
  }
  // epilogue: scatter to per-head q/k/v layouts
#pragma unroll
  for (int jc = 0; jc < 4; ++jc) {
    int gn = n0 + wn + jc * 16 + col;
#pragma unroll
    for (int ic = 0; ic < 4; ++ic)
#pragma unroll
      for (int r = 0; r < 4; ++r) {
        int gm = m0 + wm + ic * 16 + (quad << 2) + r;
        int b = gm >> 10, i = gm & 1023;
        f16 v = (f16)acc[ic][jc][r];
        if (gn < 768) {
          int h = gn >> 6, dd = gn & 63;
          qb[(((b * 12 + h) << 10) + i) * 64 + dd] = v;
        } else if (gn < 1536) {
          int t = gn - 768; int h = t >> 6, dd = t & 63;
          kb[(((b * 12 + h) << 10) + i) * 64 + dd] = v;
        } else {
          int t = gn - 1536; int h = t >> 6, dd = t & 63;
          vb[(((b * 12 + h) << 10) + i) * 64 + dd] = v;
        }
      }
  }
}

// ---------------------------------------------------------------- V transpose
__global__ __launch_bounds__(256) void k_transpose_v(const f16* __restrict__ vb,
                                                     f16* __restrict__ vt) {
  __shared__ f16 t[64 * 72];
  const int bh = blockIdx.x;        // 0..191
  const int n0 = blockIdx.y << 6;   // 16 tiles of 64
  const int tid = threadIdx.x;
#pragma unroll
  for (int s = 0; s < 2; ++s) {
    int u = s * 256 + tid;
    int r = u >> 3, c = (u & 7) << 3;
    *(f16x8*)&t[r * 72 + c] = *(const f16x8*)(vb + (bh * 1024 + n0 + r) * 64 + c);
  }
  __syncthreads();
#pragma unroll
  for (int s = 0; s < 2; ++s) {
    int u = s * 256 + tid;
    int d = u >> 3, c = (u & 7) << 3;
    f16x8 o;
#pragma unroll
    for (int e = 0; e < 8; ++e) o[e] = t[(c + e) * 72 + d];
    *(f16x8*)(vt + (bh * 64 + d) * 1024 + n0 + c) = o;
  }
}

// LDS-publishing barrier that does NOT drain vmcnt: global loads issued before
// it stay in flight across it (the compiler's counted vmcnt wait lands before
// first use).  __syncthreads() would emit s_waitcnt vmcnt(0) and kill all
// cross-barrier load overlap -- measured as the dominant stall of v1..v8.
__device__ __forceinline__ void bar_lds() {
  asm volatile("s_waitcnt lgkmcnt(0)" ::: "memory");
  __builtin_amdgcn_s_barrier();
  asm volatile("" ::: "memory");  // fence: no LDS reads hoisted above the barrier
}

// ---------------------------------------------------------------- fused attention v9
// block = 512 thr (8 waves) handles (b, 16 query rows).  32-j tiles.
// Wave w = (hh = w>>1, jh = w&1): S for 3 heads {3hh..3hh+2} over j-half jh.
// vs v8 (608us, VGPR squeezed to 64 -> spills; __syncthreads vmcnt(0) drains):
//  (a) amdgpu_waves_per_eu(4,4): allocator pinned to the LDS-permitted
//      occupancy (56KB -> 2 blocks -> 4 waves/EU) -> 128-VGPR budget, no spills.
//  (b) in-loop barriers are raw s_barrier + lgkmcnt(0) only (bar_lds above):
//      V prefetch issued before the S-barrier survives it; K loads no longer
//      force-drained every iteration.
// Layouts/math identical to v8: S units 3 heads + pad, unit swizzle (i+j)&15,
// S dbuf 16KBx2 (1 barrier/iter phase 1), Pm[12][16][8u][4] XOR (g'+i)&7 dbuf
// 12KBx2 (2 barriers/iter phase 2), maxless softmax, in-register post-mix.
__global__ __launch_bounds__(512)
__attribute__((amdgpu_waves_per_eu(4, 4))) void k_attn(
    const f16* __restrict__ qb, const f16* __restrict__ kb, const f16* __restrict__ vt,
    const float* __restrict__ mixp, const float* __restrict__ mixq,
    f16* __restrict__ ob) {
  extern __shared__ f16 smem[];
  // smem: Sbuf[2] @ 0, 8192   (each [32][4][16][4] f16 = 16KB)
  //       Pbuf[2] @ 16384, 22528 (each [12][16][8][4] f16 = 12KB)  total 56KB

  const int tid = threadIdx.x;
  const int bid0 = blockIdx.x;
  const int xcd = bid0 & 7, idx = bid0 >> 3;
  const int b = ((idx >> 6) << 3) | xcd;   // one b per XCD at a time (L2-resident)
  const int i0 = (idx & 63) << 4;
  const int lane = tid & 63;
  const int w = tid >> 6;                  // 0..7
  const int quad = lane >> 4, col = lane & 15;
  const int q4 = quad << 2;
  const int hh = w >> 1;                   // head-group 0..3 (3 heads each)
  const int jh = w & 1;                    // j-half of the 32-j tile
  const f32x4 z4 = {0.f, 0.f, 0.f, 0.f};

  // mix fragments for 16x16x16.
  // b_pre : A[m=g=col][k=4*quad+e] = mixp[head(3*quad+e)][g]  (slot e=3 is pad)
  // b_post: B[k=g=q4+e][n=g'=col]  = mixq[g][g']
  f16x4 b_pre, b_post;
#pragma unroll
  for (int e = 0; e < 4; ++e) {
    b_pre[e]  = (e < 3 && col < 12) ? (f16)mixp[(3 * quad + e) * 12 + col] : (f16)0.f;
    int hk = q4 + e;
    b_post[e] = (hk < 12 && col < 12) ? (f16)mixq[hk * 12 + col] : (f16)0.f;
  }

  // Q fragments in registers: 3 heads x 2 k-chunks (24 VGPR)
  f16x8 qf[3][2];
#pragma unroll
  for (int e = 0; e < 3; ++e)
#pragma unroll
    for (int kc = 0; kc < 2; ++kc)
      qf[e][kc] = *(const f16x8*)(qb + ((((b * 12 + 3 * hh + e) << 10) + i0 + col) << 6) +
                                  kc * 32 + quad * 8);

  // computeS: QK^T for this wave's 3 heads x 16 j -> S units in Sw.
  // unit (j = 16*jh+col, i = q4+r, hgrp = hh) at Sw[(j*4+hh)*16 + ((i+j)&15)],
  // content = heads {3hh, 3hh+1, 3hh+2, pad0}.
  auto computeS = [&](int j0, f16* Sw) {
    f16x8 kr[3][2];
#pragma unroll
    for (int e = 0; e < 3; ++e) {
      const f16* kbase =
          kb + ((((b * 12 + 3 * hh + e) << 10) + j0 + jh * 16 + col) << 6);
      kr[e][0] = *(const f16x8*)(kbase + quad * 8);
      kr[e][1] = *(const f16x8*)(kbase + 32 + quad * 8);
    }
    f32x4 s4[3];
#pragma unroll
    for (int e = 0; e < 3; ++e) {
      f32x4 a = MFMA(qf[e][0], kr[e][0], z4);
      s4[e] = MFMA(qf[e][1], kr[e][1], a);
    }
    int jj = jh * 16 + col;
#pragma unroll
    for (int r = 0; r < 4; ++r) {
      f16x4 p;
      p[0] = (f16)s4[0][r]; p[1] = (f16)s4[1][r]; p[2] = (f16)s4[2][r];
      p[3] = (f16)0.f;
      *(f16x4*)&Sw[((jj * 4 + hh) * 16 + ((q4 + r + col) & 15)) * 4] = p;
    }
  };
  // pre-mix B-frag read: lane (quad,col) reads [t][hgrp=quad][(col+t)&15]
  auto sread = [&](int t, const f16* Sw) -> f16x4 {
    return *(const f16x4*)&Sw[((t * 4 + quad) * 16 + ((col + t) & 15)) * 4];
  };

  // ---------------- phase 1: denominators l per (g,i); 1 raw barrier/iter
  float l_run[4] = {0.f, 0.f, 0.f, 0.f};
  for (int n = 0; n < 32; ++n) {
    f16* Sw = smem + (n & 1) * 8192;
    computeS(n * 32, Sw);
    bar_lds();
    f16x4 sB[4];
#pragma unroll
    for (int t4 = 0; t4 < 4; ++t4) sB[t4] = sread(w * 4 + t4, Sw);
#pragma unroll
    for (int t4 = 0; t4 < 4; ++t4) {
      f32x4 d1 = MFMA16(b_pre, sB[t4], z4);
#pragma unroll
      for (int r = 0; r < 4; ++r) l_run[r] += __expf(d1[r]);
    }
  }
  // merge partial l across the 8 waves
  float* Lb = (float*)(smem + 16384);  // overlays Pbuf[0], phase boundary only
#pragma unroll
  for (int r = 0; r < 4; ++r) Lb[(w * 16 + q4 + r) * 16 + col] = l_run[r];
  __syncthreads();
  float il[4];
#pragma unroll
  for (int r = 0; r < 4; ++r) {
    float s = 0.f;
#pragma unroll
    for (int ww = 0; ww < 8; ++ww) s += Lb[(ww * 16 + q4 + r) * 16 + col];
    il[r] = 1.f / s;
  }
  __syncthreads();  // Lb handed back to Pm

  // ---------------- phase 2: recompute S, P=exp*il, post-mix, PV
  f32x4 oa[3][2];
#pragma unroll
  for (int u3 = 0; u3 < 3; ++u3) { oa[u3][0] = z4; oa[u3][1] = z4; }

  for (int n = 0; n < 32; ++n) {
    int j0 = n * 32;
    f16* Sw = smem + (n & 1) * 8192;
    f16* Pm = smem + 16384 + (n & 1) * 6144;
    computeS(j0, Sw);
    // V prefetch (independent of S/Pm): stays in flight across the raw barrier,
    // lands under the mix/exp VALU work, consumed by PV after the 2nd barrier.
    f16x8 vr[3][2];
#pragma unroll
    for (int u3 = 0; u3 < 3; ++u3) {
      int u = w * 3 + u3, gp = u >> 1, dh = u & 1;
#pragma unroll
      for (int dc = 0; dc < 2; ++dc)
        vr[u3][dc] = *(const f16x8*)(vt +
            ((((b * 12 + gp) << 6) + dh * 32 + dc * 16 + col) << 10) + j0 + quad * 8);
    }
    bar_lds();  // S complete (lgkm only; V loads NOT drained)
    f16x4 sB[4];
#pragma unroll
    for (int t4 = 0; t4 < 4; ++t4) sB[t4] = sread(w * 4 + t4, Sw);
    f16x4 pk[4];
#pragma unroll
    for (int t4 = 0; t4 < 4; ++t4) {
      f32x4 d1 = MFMA16(b_pre, sB[t4], z4);
      f16x4 pA;
#pragma unroll
      for (int r = 0; r < 4; ++r) pA[r] = (f16)(__expf(d1[r]) * il[r]);
      f32x4 d2 = MFMA16(pA, b_post, z4);  // lane: (i=q4+r, g'=col, j=w*4+t4)
#pragma unroll
      for (int r = 0; r < 4; ++r) pk[r][t4] = (f16)d2[r];
    }
    // Pm write: unit w of row (g'=col, i=q4+r), XOR key (g'+i)&7
    if (col < 12) {
#pragma unroll
      for (int r = 0; r < 4; ++r) {
        int k4 = (col + q4 + r) & 7;
        *(f16x4*)&Pm[(((col << 4) + q4 + r) * 8 + (w ^ k4)) * 4] = pk[r];
      }
    }
    bar_lds();  // Pm complete
    // PV: wave owns units 3w..3w+2 of the 24 (head, d-half) pairs
#pragma unroll
    for (int u3 = 0; u3 < 3; ++u3) {
      int u = w * 3 + u3, gp = u >> 1;
      int k4r = (gp + col) & 7;
      f16x4 lo = *(const f16x4*)&Pm[(((gp << 4) + col) * 8 + ((quad * 2) ^ k4r)) * 4];
      f16x4 hi = *(const f16x4*)&Pm[(((gp << 4) + col) * 8 + ((quad * 2 + 1) ^ k4r)) * 4];
      f16x8 aP = __builtin_shufflevector(lo, hi, 0, 1, 2, 3, 4, 5, 6, 7);
#pragma unroll
      for (int dc = 0; dc < 2; ++dc)
        oa[u3][dc] = MFMA(aP, vr[u3][dc], oa[u3][dc]);
    }
  }

  // epilogue: O (C-layout: row=q4+r = i, col -> d) -> obuf [b][n][768]
#pragma unroll
  for (int u3 = 0; u3 < 3; ++u3) {
    int u = w * 3 + u3, gp = u >> 1, dh = u & 1;
#pragma unroll
    for (int dc = 0; dc < 2; ++dc)
#pragma unroll
      for (int r = 0; r < 4; ++r)
        ob[((b << 10) + i0 + q4 + r) * 768 + gp * 64 + dh * 32 + dc * 16 + col] =
            (f16)oa[u3][dc][r];
  }
}

// ---------------------------------------------------------------- output GEMM
__global__ __launch_bounds__(256) void k_gemm_out(const f16* __restrict__ A,
                                                  const f16* __restrict__ Bt,
                                                  const float* __restrict__ bias,
                                                  float* __restrict__ out) {
  __shared__ f16 As[128 * 72];
  __shared__ f16 Bs[128 * 72];
  const int tid = threadIdx.x;
  const int m0 = blockIdx.y << 7;
  const int n0 = blockIdx.x << 7;
  const int lane = tid & 63, w = tid >> 6;
  const int quad = lane >> 4, col = lane & 15;
  const int wm = (w >> 1) << 6, wn = (w & 1) << 6;
  const f32x4 z4 = {0.f, 0.f, 0.f, 0.f};
  f32x4 acc[4][4];
#pragma unroll
  for (int i = 0; i < 4; ++i)
#pragma unroll
    for (int j = 0; j < 4; ++j) acc[i][j] = z4;

  for (int k0 = 0; k0 < 768; k0 += 64) {
#pragma unroll
    for (int s = 0; s < 4; ++s) {
      int u = s * 256 + tid;
      int row = u >> 3, seg = (u & 7) << 3;
      *(f16x8*)&As[row * 72 + seg] = *(const f16x8*)(A + (m0 + row) * 768 + k0 + seg);
      *(f16x8*)&Bs[row * 72 + seg] = *(const f16x8*)(Bt + (n0 + row) * 768 + k0 + seg);
    }
    __syncthreads();
#pragma unroll
    for (int kk = 0; kk < 64; kk += 32) {
      f16x8 af[4], bf[4];
#pragma unroll
      for (int ic = 0; ic < 4; ++ic)
        af[ic] = *(f16x8*)&As[(wm + ic * 16 + col) * 72 + kk + quad * 8];
#pragma unroll
      for (int jc = 0; jc < 4; ++jc)
        bf[jc] = *(f16x8*)&Bs[(wn + jc * 16 + col) * 72 + kk + quad * 8];
#pragma unroll
      for (int ic = 0; ic < 4; ++ic)
#pragma unroll
        for (int jc = 0; jc < 4; ++jc) acc[ic][jc] = MFMA(af[ic], bf[jc], acc[ic][jc]);
    }
    __syncthreads();
  }
#pragma unroll
  for (int jc = 0; jc < 4; ++jc) {
    int gn = n0 + wn + jc * 16 + col;
    float bv = bias[gn];
#pragma unroll
    for (int ic = 0; ic < 4; ++ic)
#pragma unroll
      for (int r = 0; r < 4; ++r) {
        int gm = m0 + wm + ic * 16 + (quad << 2) + r;
        out[gm * 768 + gn] = acc[ic][jc][r] + bv;
      }
  }
}

// ---------------------------------------------------------------- launcher
extern "C" void kernel_launch(void* const* d_in, const int* in_sizes, int n_in,
                              void* d_out, int out_size, void* d_ws, size_t ws_size,
                              hipStream_t stream) {
  const float* x    = (const float*)d_in[0];
  const float* Wq   = (const float*)d_in[1];
  const float* Wkv  = (const float*)d_in[2];
  const float* mixp = (const float*)d_in[3];
  const float* mixq = (const float*)d_in[4];
  const float* Wo   = (const float*)d_in[5];
  const float* bo   = (const float*)d_in[6];
  float* out = (float*)d_out;

  char* ws = (char*)d_ws;
  f16* xb  = (f16*)(ws);
  f16* Wt  = (f16*)(ws + 25165824);
  f16* WoT = (f16*)(ws + 28704768);
  f16* qb  = (f16*)(ws + 29884416);
  f16* kb  = (f16*)(ws + 55050240);
  f16* vb  = (f16*)(ws + 80216064);
  f16* vt  = xb;   // xb dead after k_gemm_qkv
  f16* obuf = vb;  // vb dead after k_transpose_v

  k_cast_x<<<dim3(6144), dim3(256), 0, stream>>>(x, xb);
  k_prep_w<<<dim3(9216), dim3(256), 0, stream>>>(Wq, Wkv, Wo, Wt, WoT);
  k_gemm_qkv<<<dim3(18, 128), dim3(256), 0, stream>>>(xb, Wt, qb, kb, vb);
  k_transpose_v<<<dim3(192, 16), dim3(256), 0, stream>>>(vb, vt);
  k_attn<<<dim3(1024), dim3(512), 57344, stream>>>(qb, kb, vt, mixp, mixq, obuf);
  k_gemm_out<<<dim3(6, 128), dim3(256), 0, stream>>>(obuf, WoT, bo, out);
}